// Round 1
// baseline (8666.811 us; speedup 1.0000x reference)
//
#include <hip/hip_runtime.h>
#include <math.h>

#define B_ 8
#define S_ 2
#define L_ 32000
#define T_ 497
#define AE 256
#define NFREQ 129
#define FC 385
#define BTL 256
#define H_ 512
#define NB 32
#define EMBED 20
#define KB (T_*FC)
#define NPAIR 15
#define MEPS 1e-12f
#define PI2F 6.28318530717958647692f

// ---------------- workspace layout (floats) ----------------
static constexpr size_t ALGN(size_t x){ return (x + 63) & ~(size_t)63; }
static constexpr size_t o_mix  = 0;
static constexpr size_t o_dftB = ALGN(o_mix + (size_t)B_*L_);
static constexpr size_t o_spec = ALGN(o_dftB + (size_t)256*258);
static constexpr size_t o_enc  = ALGN(o_spec + (size_t)B_*T_*258);
static constexpr size_t o_mag  = ALGN(o_enc + (size_t)B_*T_*AE);
static constexpr size_t o_cosp = ALGN(o_mag + (size_t)B_*T_*NFREQ);
static constexpr size_t o_sinp = ALGN(o_cosp + (size_t)B_*T_*NFREQ);
static constexpr size_t o_xln  = ALGN(o_sinp + (size_t)B_*T_*NFREQ);
static constexpr size_t o_x    = ALGN(o_xln + (size_t)B_*T_*FC);
static constexpr size_t o_y    = ALGN(o_x + (size_t)B_*T_*BTL);
static constexpr size_t o_z    = ALGN(o_y + (size_t)B_*T_*H_);
static constexpr size_t o_gsum = ALGN(o_z + (size_t)B_*T_*H_);   // 32 blocks * 32 floats
static constexpr size_t o_acc  = o_gsum + 1024;                  // B*15*2*21 = 5040
static constexpr size_t o_att  = ALGN(o_acc + (size_t)B_*NPAIR*2*21);
static constexpr size_t o_decB = ALGN(o_att + (size_t)B_*2*EMBED);
static constexpr size_t o_decBias = ALGN(o_decB + (size_t)514*256);
static constexpr size_t o_emb  = ALGN(o_decBias + 256);
static constexpr size_t o_D    = ALGN(o_emb + (size_t)B_*KB*EMBED);
static constexpr size_t o_Af   = o_D;   // alias: D dead before Afull written (7952*514 <= B*KB*6)
static constexpr size_t o_fr   = o_y;   // alias: ybuf dead before dec GEMM (same size)

// ---------------- small kernels ----------------
__global__ __launch_bounds__(256) void k_mix(const float* __restrict__ aud, float* __restrict__ mix){
  int i = blockIdx.x*256 + threadIdx.x;
  if (i < B_*L_){
    int b = i / L_, l = i % L_;
    mix[i] = aud[((size_t)b*S_+0)*L_ + l] + aud[((size_t)b*S_+1)*L_ + l];
  }
}

__global__ __launch_bounds__(256) void k_dftb(float* __restrict__ dftB){
  int i = blockIdx.x*256 + threadIdx.x;
  if (i < 256*258){
    int k = i / 258, n = i % 258;
    float win = sqrtf(0.5f - 0.5f*cosf(PI2F * (float)k / 256.0f));
    int f = (n < NFREQ) ? n : (n - NFREQ);
    int m = (k * f) & 255;
    float th = PI2F * (float)m / 256.0f;
    dftB[i] = (n < NFREQ) ? win * cosf(th) : -win * sinf(th);
  }
}

__global__ __launch_bounds__(256) void k_decb(const float* __restrict__ dec_w, const float* __restrict__ dec_b,
                                              float* __restrict__ decB, float* __restrict__ decBias){
  int i = blockIdx.x*256 + threadIdx.x;
  if (i < 514*256){
    int k = i / 256, n = i & 255;
    float v;
    if (k < 256){
      v = 0.5f * dec_w[(size_t)k*256 + n];
    } else {
      int m = n & 63;
      float den = 0.f;
      #pragma unroll
      for (int j = 0; j < 4; j++) den += 0.5f - 0.5f*cosf(PI2F*(float)(m + 64*j)/256.0f);
      float win = sqrtf(0.5f - 0.5f*cosf(PI2F*(float)n/256.0f));
      float iw = win / den;
      int f = (k < 385) ? (k - 256) : (k - 385);
      int mm = (f * n) & 255;
      float th = PI2F * (float)mm / 256.0f;
      if (k < 385){
        float cf = (f==0 || f==128) ? 1.0f : 2.0f;
        v = 0.5f * iw * cf * cosf(th) * (1.0f/256.0f);
      } else {
        v = (f==0 || f==128) ? 0.0f : -1.0f * iw * sinf(th) * (1.0f/256.0f); // 0.5*2
      }
    }
    decB[i] = v;
    if (i < 256) decBias[i] = 0.5f * dec_b[i];
  }
}

// ---------------- frames GEMM (A gathered from mix), K=256 ----------------
__global__ __launch_bounds__(256) void gemm_frames(
    const float* __restrict__ mix, const float* __restrict__ Bm,
    const float* __restrict__ bias, float* __restrict__ C, int N, int relu){
  const int M = B_*T_, K = 256;
  __shared__ float As[16][68];
  __shared__ float Bs[16][68];
  const int tid = threadIdx.x;
  const int tx = tid & 15, ty = tid >> 4;
  const int row0 = blockIdx.y*64, col0 = blockIdx.x*64;
  const int am = tid >> 2, ak = (tid & 3) * 4;
  const int bkk = tid >> 4, bn = (tid & 15) * 4;
  const int arow = row0 + am;
  const float* aptr = nullptr;
  if (arow < M){ int b = arow / T_, t = arow % T_; aptr = mix + (size_t)b*L_ + t*64; }
  float acc[4][4] = {};
  for (int k0 = 0; k0 < K; k0 += 16){
    #pragma unroll
    for (int i = 0; i < 4; i++)
      As[ak+i][am] = aptr ? aptr[k0+ak+i] : 0.f;
    #pragma unroll
    for (int i = 0; i < 4; i++){
      int n = col0 + bn + i;
      Bs[bkk][bn+i] = (n < N) ? Bm[(size_t)(k0+bkk)*N + n] : 0.f;
    }
    __syncthreads();
    #pragma unroll
    for (int kk = 0; kk < 16; kk++){
      float av[4], bv[4];
      #pragma unroll
      for (int i = 0; i < 4; i++) av[i] = As[kk][ty*4+i];
      #pragma unroll
      for (int j = 0; j < 4; j++) bv[j] = Bs[kk][tx*4+j];
      #pragma unroll
      for (int i = 0; i < 4; i++)
        #pragma unroll
        for (int j = 0; j < 4; j++) acc[i][j] = fmaf(av[i], bv[j], acc[i][j]);
    }
    __syncthreads();
  }
  #pragma unroll
  for (int i = 0; i < 4; i++){
    int r = row0 + ty*4 + i;
    if (r >= M) continue;
    #pragma unroll
    for (int j = 0; j < 4; j++){
      int c = col0 + tx*4 + j;
      if (c >= N) continue;
      float v = acc[i][j] + (bias ? bias[c] : 0.f);
      if (relu) v = fmaxf(v, 0.f);
      C[(size_t)r*N + c] = v;
    }
  }
}

// ---------------- generic GEMM ----------------
// ALOAD: 0 plain A, 1 gLN-affine on A load (needs aff_g, aff_b, gsumIn)
// EPI:   0 bias only, 1 bias+PReLU+store+partial sums (BUNIF grid), 2 bias+residual
template<int ALOAD, int EPI, bool BUNIF>
__global__ __launch_bounds__(256) void gemm_g(
    const float* __restrict__ A, const float* __restrict__ Bm,
    const float* __restrict__ bias, float* __restrict__ C,
    int M, int N, int K,
    const float* __restrict__ aff_g, const float* __restrict__ aff_b,
    const float* __restrict__ gsumIn,
    const float* __restrict__ prelu_a, float* __restrict__ gsumOut,
    const float* __restrict__ resid)
{
  __shared__ float As[16][68];
  __shared__ float Bs[16][68];
  __shared__ float red[8];
  const int tid = threadIdx.x;
  const int tx = tid & 15, ty = tid >> 4;
  const int row0 = blockIdx.y * 64, col0 = blockIdx.x * 64;
  const int rbase = BUNIF ? (int)blockIdx.z * T_ : 0;
  const int am = tid >> 2, ak = (tid & 3) * 4;
  const int bkk = tid >> 4, bn = (tid & 15) * 4;
  const int arow_l = row0 + am;
  const bool aok = arow_l < M;
  const float* aptr = nullptr;
  float a_mean = 0.f, a_rstd = 0.f;
  if (aok){
    int row_ga = rbase + arow_l;
    aptr = A + (size_t)row_ga * K;
    if (ALOAD == 1){
      int b = row_ga / T_;
      float icnt = 1.0f / ((float)T_ * (float)K);
      float s = gsumIn[b*2], ss = gsumIn[b*2+1];
      a_mean = s * icnt;
      float var = ss * icnt - a_mean * a_mean;
      a_rstd = rsqrtf(var + MEPS);
    }
  }
  float acc[4][4] = {};
  for (int k0 = 0; k0 < K; k0 += 16){
    #pragma unroll
    for (int i = 0; i < 4; i++){
      int k = k0 + ak + i;
      float v = 0.f;
      if (aok && k < K){
        float raw = aptr[k];
        if (ALOAD == 1) v = (raw - a_mean) * a_rstd * aff_g[k] + aff_b[k];
        else v = raw;
      }
      As[ak+i][am] = v;
    }
    #pragma unroll
    for (int i = 0; i < 4; i++){
      int n = col0 + bn + i;
      int k = k0 + bkk;
      Bs[bkk][bn+i] = (k < K && n < N) ? Bm[(size_t)k * N + n] : 0.f;
    }
    __syncthreads();
    #pragma unroll
    for (int kk = 0; kk < 16; kk++){
      float av[4], bv[4];
      #pragma unroll
      for (int i = 0; i < 4; i++) av[i] = As[kk][ty*4+i];
      #pragma unroll
      for (int j = 0; j < 4; j++) bv[j] = Bs[kk][tx*4+j];
      #pragma unroll
      for (int i = 0; i < 4; i++)
        #pragma unroll
        for (int j = 0; j < 4; j++) acc[i][j] = fmaf(av[i], bv[j], acc[i][j]);
    }
    __syncthreads();
  }
  float ps = 0.f, pss = 0.f;
  #pragma unroll
  for (int i = 0; i < 4; i++){
    int r_l = row0 + ty*4 + i;
    if (r_l >= M) continue;
    size_t r_g = (size_t)(rbase + r_l);
    #pragma unroll
    for (int j = 0; j < 4; j++){
      int c = col0 + tx*4 + j;
      if (c >= N) continue;
      float v = acc[i][j] + (bias ? bias[c] : 0.f);
      if (EPI == 1){
        float p = fmaxf(v, 0.f) + prelu_a[c] * fminf(v, 0.f);
        C[r_g * N + c] = p;
        ps += p; pss += p * p;
      } else if (EPI == 2){
        C[r_g * N + c] = v + resid[r_g * N + c];
      } else {
        C[r_g * N + c] = v;
      }
    }
  }
  if (EPI == 1){
    #pragma unroll
    for (int off = 32; off > 0; off >>= 1){
      ps  += __shfl_down(ps, off);
      pss += __shfl_down(pss, off);
    }
    if ((tid & 63) == 0){ red[(tid>>6)*2] = ps; red[(tid>>6)*2+1] = pss; }
    __syncthreads();
    if (tid == 0){
      float s  = red[0] + red[2] + red[4] + red[6];
      float ss = red[1] + red[3] + red[5] + red[7];
      atomicAdd(&gsumOut[blockIdx.z*2],     s);
      atomicAdd(&gsumOut[blockIdx.z*2 + 1], ss);
    }
  }
}

// ---------------- cLN over [enc | log1p(mag)] ----------------
__global__ __launch_bounds__(256) void k_cln(
    const float* __restrict__ spec, const float* __restrict__ enc,
    const float* __restrict__ gamma, const float* __restrict__ beta,
    float* __restrict__ mag, float* __restrict__ cosp, float* __restrict__ sinp,
    float* __restrict__ xln){
  int t = blockIdx.x, b = blockIdx.y, tid = threadIdx.x;
  size_t row = (size_t)b*T_ + t;
  __shared__ float feat[FC];
  __shared__ float red[8];
  feat[tid] = enc[row*AE + tid];
  if (tid < NFREQ){
    float re = spec[row*258 + tid], im = spec[row*258 + NFREQ + tid];
    float m = sqrtf(re*re + im*im);
    mag[row*NFREQ + tid] = m;
    float c = 1.f, s = 0.f;
    if (m > 0.f){ c = re/m; s = im/m; }
    cosp[row*NFREQ + tid] = c;
    sinp[row*NFREQ + tid] = s;
    feat[AE + tid] = log1pf(m);
  }
  __syncthreads();
  float v = feat[tid] + ((tid < FC-256) ? feat[256+tid] : 0.f);
  #pragma unroll
  for (int off = 32; off > 0; off >>= 1) v += __shfl_down(v, off);
  if ((tid & 63) == 0) red[tid>>6] = v;
  __syncthreads();
  float mean = (red[0]+red[1]+red[2]+red[3]) * (1.0f/FC);
  float d0 = feat[tid] - mean;
  float vv = d0*d0;
  if (tid < FC-256){ float d1 = feat[256+tid] - mean; vv += d1*d1; }
  __syncthreads();
  #pragma unroll
  for (int off = 32; off > 0; off >>= 1) vv += __shfl_down(vv, off);
  if ((tid & 63) == 0) red[tid>>6] = vv;
  __syncthreads();
  float var = (red[0]+red[1]+red[2]+red[3]) * (1.0f/FC);
  float rstd = rsqrtf(var + MEPS);
  xln[row*FC + tid] = (feat[tid]-mean)*rstd*gamma[tid] + beta[tid];
  if (tid < FC-256)
    xln[row*FC + 256+tid] = (feat[256+tid]-mean)*rstd*gamma[256+tid] + beta[256+tid];
}

// ---------------- dilated depthwise conv with gLN-affine on load ----------------
__global__ __launch_bounds__(256) void k_dwconv(
    const float* __restrict__ ybuf, const float* __restrict__ dw,
    const float* __restrict__ g1g, const float* __restrict__ g1b,
    const float* __restrict__ gsum1, const float* __restrict__ p2a,
    float* __restrict__ zbuf, float* __restrict__ gsum2, int dil){
  int t = blockIdx.x, b = blockIdx.y, tid = threadIdx.x;
  float icnt = 1.0f / ((float)T_ * (float)H_);
  float m = gsum1[b*2] * icnt;
  float var = gsum1[b*2+1] * icnt - m*m;
  float rstd = rsqrtf(var + MEPS);
  __shared__ float red[8];
  float ps = 0.f, pss = 0.f;
  for (int c = tid; c < H_; c += 256){
    float g = g1g[c] * rstd;
    float bb = g1b[c] - m * g;
    float z = 0.f;
    #pragma unroll
    for (int kk = 0; kk < 3; kk++){
      int tt = t + (kk-1)*dil;
      if (tt >= 0 && tt < T_){
        float p = ybuf[((size_t)b*T_ + tt)*H_ + c];
        z += dw[kk*H_ + c] * (p*g + bb);
      }
    }
    float p2 = fmaxf(z, 0.f) + p2a[c] * fminf(z, 0.f);
    zbuf[((size_t)b*T_ + t)*H_ + c] = p2;
    ps += p2; pss += p2*p2;
  }
  #pragma unroll
  for (int off = 32; off > 0; off >>= 1){
    ps  += __shfl_down(ps, off);
    pss += __shfl_down(pss, off);
  }
  if ((tid & 63) == 0){ red[(tid>>6)*2] = ps; red[(tid>>6)*2+1] = pss; }
  __syncthreads();
  if (tid == 0){
    float s  = red[0] + red[2] + red[4] + red[6];
    float ss = red[1] + red[3] + red[5] + red[7];
    atomicAdd(&gsum2[b*2],     s);
    atomicAdd(&gsum2[b*2 + 1], ss);
  }
}

// ---------------- anchor dots ----------------
__global__ __launch_bounds__(256) void k_dots(const float* __restrict__ emb,
                                              const float* __restrict__ anchors,
                                              float* __restrict__ D){
  __shared__ float anc[6][20];
  int tid = threadIdx.x;
  if (tid < 120) anc[tid/20][tid%20] = anchors[tid];
  __syncthreads();
  size_t i = (size_t)blockIdx.x*256 + tid;
  if (i < (size_t)B_*KB){
    const float* e = emb + i*20;
    float ev[20];
    #pragma unroll
    for (int j = 0; j < 20; j++) ev[j] = e[j];
    #pragma unroll
    for (int c = 0; c < 6; c++){
      float d = 0.f;
      #pragma unroll
      for (int j = 0; j < 20; j++) d = fmaf(ev[j], anc[c][j], d);
      D[i*6 + c] = d;
    }
  }
}

// ---------------- attractor accumulation ----------------
__global__ __launch_bounds__(256) void k_attr(const float* __restrict__ emb,
                                              const float* __restrict__ D,
                                              float* __restrict__ acc){
  const int c0a[15] = {0,0,0,0,0,1,1,1,1,2,2,2,3,3,4};
  const int c1a[15] = {1,2,3,4,5,2,3,4,5,3,4,5,4,5,5};
  int b = blockIdx.y, tid = threadIdx.x;
  __shared__ float eS[64][20];
  __shared__ float dS[64][6];
  __shared__ float sS[64][30];
  float a0 = 0.f, a1 = 0.f, a2 = 0.f;
  const int o0 = tid, o1 = tid + 256, o2 = tid + 512;
  const int NCH = (KB + 63) / 64;
  for (int ch = blockIdx.x; ch < NCH; ch += gridDim.x){
    int k0 = ch * 64;
    for (int idx = tid; idx < 64*20; idx += 256){
      int kk = idx / 20, e = idx % 20, gk = k0 + kk;
      eS[kk][e] = (gk < KB) ? emb[((size_t)b*KB + gk)*20 + e] : 0.f;
    }
    for (int idx = tid; idx < 64*6; idx += 256){
      int kk = idx / 6, c = idx % 6, gk = k0 + kk;
      dS[kk][c] = (gk < KB) ? D[((size_t)b*KB + gk)*6 + c] : 0.f;
    }
    __syncthreads();
    for (int idx = tid; idx < 64*15; idx += 256){
      int kk = idx / 15, p = idx % 15, gk = k0 + kk;
      float s0 = 0.f, s1 = 0.f;
      if (gk < KB){
        float d0 = dS[kk][c0a[p]], d1 = dS[kk][c1a[p]];
        s0 = 1.0f / (1.0f + expf(d1 - d0));
        s1 = 1.0f - s0;
      }
      sS[kk][2*p]   = s0;
      sS[kk][2*p+1] = s1;
    }
    __syncthreads();
    {
      int pc = o0 / 21, e = o0 % 21;
      float s = 0.f;
      if (e < 20){ for (int kk = 0; kk < 64; kk++) s = fmaf(sS[kk][pc], eS[kk][e], s); }
      else       { for (int kk = 0; kk < 64; kk++) s += sS[kk][pc]; }
      a0 += s;
    }
    {
      int pc = o1 / 21, e = o1 % 21;
      float s = 0.f;
      if (e < 20){ for (int kk = 0; kk < 64; kk++) s = fmaf(sS[kk][pc], eS[kk][e], s); }
      else       { for (int kk = 0; kk < 64; kk++) s += sS[kk][pc]; }
      a1 += s;
    }
    if (o2 < 630){
      int pc = o2 / 21, e = o2 % 21;
      float s = 0.f;
      if (e < 20){ for (int kk = 0; kk < 64; kk++) s = fmaf(sS[kk][pc], eS[kk][e], s); }
      else       { for (int kk = 0; kk < 64; kk++) s += sS[kk][pc]; }
      a2 += s;
    }
    __syncthreads();
  }
  atomicAdd(&acc[b*630 + o0], a0);
  atomicAdd(&acc[b*630 + o1], a1);
  if (o2 < 630) atomicAdd(&acc[b*630 + o2], a2);
}

// ---------------- attractor normalize + select ----------------
__global__ __launch_bounds__(128) void k_attrfin(const float* __restrict__ acc,
                                                 float* __restrict__ attractors){
  __shared__ float aN[120][40];
  __shared__ float sp[120];
  int tid = threadIdx.x;
  if (tid < 120){
    const float* a = acc + (size_t)tid*42;
    for (int c = 0; c < 2; c++){
      float den = a[c*21 + 20];
      for (int e = 0; e < 20; e++) aN[tid][c*20 + e] = a[c*21 + e] / den;
    }
    float s = 0.f;
    for (int e = 0; e < 20; e++) s = fmaf(aN[tid][e], aN[tid][20+e], s);
    sp[tid] = s;
  }
  __syncthreads();
  if (tid < B_){
    int base = tid * 15, best = 0;
    float bv = sp[base];
    for (int p = 1; p < 15; p++) if (sp[base+p] < bv){ bv = sp[base+p]; best = p; }
    for (int i = 0; i < 40; i++) attractors[tid*40 + i] = aN[base+best][i];
  }
}

// ---------------- build decoder-GEMM A rows ----------------
__global__ __launch_bounds__(256) void k_afull(
    const float* __restrict__ emb, const float* __restrict__ enc,
    const float* __restrict__ mag, const float* __restrict__ cosp,
    const float* __restrict__ sinp, const float* __restrict__ attractors,
    float* __restrict__ Af){
  int t = blockIdx.x, b = blockIdx.y, tid = threadIdx.x;
  __shared__ float att[40];
  if (tid < 40) att[tid] = attractors[b*40 + tid];
  __syncthreads();
  size_t row = (size_t)b*T_ + t;
  size_t r0 = ((size_t)(b*2+0)*T_ + t)*514;
  size_t r1 = ((size_t)(b*2+1)*T_ + t)*514;
  for (int f = tid; f < FC; f += 256){
    const float* e = emb + (row*FC + f)*20;
    float l0 = 0.f, l1 = 0.f;
    #pragma unroll
    for (int j = 0; j < 20; j++){
      float ev = e[j];
      l0 = fmaf(ev, att[j],    l0);
      l1 = fmaf(ev, att[20+j], l1);
    }
    if (f < AE){
      float ft = enc[row*AE + f];
      Af[r0 + f] = l0*ft;
      Af[r1 + f] = l1*ft;
    } else {
      int fi = f - AE;
      float ft = mag[row*NFREQ + fi];
      float c = cosp[row*NFREQ + fi], s = sinp[row*NFREQ + fi];
      float s0 = l0*ft, s1v = l1*ft;
      Af[r0 + 256 + fi] = c*s0;  Af[r0 + 385 + fi] = s*s0;
      Af[r1 + 256 + fi] = c*s1v; Af[r1 + 385 + fi] = s*s1v;
    }
  }
}

// ---------------- overlap-add gather ----------------
__global__ __launch_bounds__(256) void k_ola(const float* __restrict__ frames,
                                             float* __restrict__ out){
  int i = blockIdx.x*256 + threadIdx.x;
  if (i < B_*2*L_){
    int bs = i / L_, l = i % L_;
    int t0 = l >> 6;
    float s = 0.f;
    #pragma unroll
    for (int j = 0; j < 4; j++){
      int t = t0 - j;
      if (t >= 0 && t < T_){
        int k = l - t*64;
        s += frames[((size_t)bs*T_ + t)*256 + k];
      }
    }
    out[i] = s;
  }
}

// ---------------- launcher ----------------
extern "C" void kernel_launch(void* const* d_in, const int* in_sizes, int n_in,
                              void* d_out, int out_size, void* d_ws, size_t ws_size,
                              hipStream_t stream) {
  const float* audios   = (const float*)d_in[0];
  const float* enc_w    = (const float*)d_in[1];
  const float* enc_b    = (const float*)d_in[2];
  const float* bgamma   = (const float*)d_in[3];
  const float* bbeta    = (const float*)d_in[4];
  const float* bottle_w = (const float*)d_in[5];
  const float* bottle_b = (const float*)d_in[6];
  const float* c1_w     = (const float*)d_in[7];
  const float* c1_b     = (const float*)d_in[8];
  const float* p1       = (const float*)d_in[9];
  const float* g1_g     = (const float*)d_in[10];
  const float* g1_b     = (const float*)d_in[11];
  const float* dwp      = (const float*)d_in[12];
  const float* p2       = (const float*)d_in[13];
  const float* g2_g     = (const float*)d_in[14];
  const float* g2_b     = (const float*)d_in[15];
  const float* c2_w     = (const float*)d_in[16];
  const float* c2_b     = (const float*)d_in[17];
  const float* sep_w    = (const float*)d_in[18];
  const float* sep_b    = (const float*)d_in[19];
  const float* anchors  = (const float*)d_in[20];
  const float* dec_w    = (const float*)d_in[21];
  const float* dec_b    = (const float*)d_in[22];

  float* ws = (float*)d_ws;
  float* mix   = ws + o_mix;
  float* dftB  = ws + o_dftB;
  float* spec  = ws + o_spec;
  float* enc   = ws + o_enc;
  float* mag   = ws + o_mag;
  float* cosp  = ws + o_cosp;
  float* sinp  = ws + o_sinp;
  float* xln   = ws + o_xln;
  float* xbuf  = ws + o_x;
  float* ybuf  = ws + o_y;
  float* zbuf  = ws + o_z;
  float* gsum  = ws + o_gsum;
  float* accp  = ws + o_acc;
  float* attp  = ws + o_att;
  float* decB  = ws + o_decB;
  float* decBias = ws + o_decBias;
  float* embp  = ws + o_emb;
  float* Dp    = ws + o_D;
  float* Afull = ws + o_Af;
  float* framesp = ws + o_fr;

  // zero the atomic accumulators (gsum 1024 + attr acc 5040, contiguous)
  hipMemsetAsync((void*)gsum, 0, (1024 + (size_t)B_*NPAIR*2*21) * sizeof(float), stream);

  k_mix <<<(B_*L_ + 255)/256, 256, 0, stream>>>(audios, mix);
  k_dftb<<<(256*258 + 255)/256, 256, 0, stream>>>(dftB);
  k_decb<<<(514*256 + 255)/256, 256, 0, stream>>>(dec_w, dec_b, decB, decBias);

  // encoder + spectrum
  gemm_frames<<<dim3(4, 63), 256, 0, stream>>>(mix, enc_w, enc_b, enc, 256, 1);
  gemm_frames<<<dim3(5, 63), 256, 0, stream>>>(mix, dftB, nullptr, spec, 258, 0);

  k_cln<<<dim3(T_, B_), 256, 0, stream>>>(spec, enc, bgamma, bbeta, mag, cosp, sinp, xln);

  // bottleneck
  gemm_g<0,0,false><<<dim3(4, 63), 256, 0, stream>>>(
      xln, bottle_w, bottle_b, xbuf, B_*T_, BTL, FC,
      nullptr, nullptr, nullptr, nullptr, nullptr, nullptr);

  // TCN
  for (int i = 0; i < NB; i++){
    int dil = 1 << (i & 7);
    gemm_g<0,1,true><<<dim3(8, 8, B_), 256, 0, stream>>>(
        xbuf, c1_w + (size_t)i*BTL*H_, c1_b + i*H_, ybuf, T_, H_, BTL,
        nullptr, nullptr, nullptr, p1 + i*H_, gsum + i*32, nullptr);
    k_dwconv<<<dim3(T_, B_), 256, 0, stream>>>(
        ybuf, dwp + (size_t)i*3*H_, g1_g + i*H_, g1_b + i*H_,
        gsum + i*32, p2 + i*H_, zbuf, gsum + i*32 + 16, dil);
    gemm_g<1,2,false><<<dim3(4, 63), 256, 0, stream>>>(
        zbuf, c2_w + (size_t)i*H_*BTL, c2_b + i*BTL, xbuf, B_*T_, BTL, H_,
        g2_g + i*H_, g2_b + i*H_, gsum + i*32 + 16, nullptr, nullptr, xbuf);
  }

  // separator
  gemm_g<0,0,false><<<dim3(121, 63), 256, 0, stream>>>(
      xbuf, sep_w, sep_b, embp, B_*T_, FC*EMBED, BTL,
      nullptr, nullptr, nullptr, nullptr, nullptr, nullptr);

  // attractors
  k_dots<<<((int)((size_t)B_*KB + 255)/256), 256, 0, stream>>>(embp, anchors, Dp);
  k_attr<<<dim3(30, B_), 256, 0, stream>>>(embp, Dp, accp);
  k_attrfin<<<1, 128, 0, stream>>>(accp, attp);

  // decode
  k_afull<<<dim3(T_, B_), 256, 0, stream>>>(embp, enc, mag, cosp, sinp, attp, Afull);
  gemm_g<0,0,false><<<dim3(4, 125), 256, 0, stream>>>(
      Afull, decB, decBias, framesp, 2*B_*T_, 256, 514,
      nullptr, nullptr, nullptr, nullptr, nullptr, nullptr);
  k_ola<<<(B_*2*L_ + 255)/256, 256, 0, stream>>>(framesp, (float*)d_out);
}

// Round 3
// 7798.389 us; speedup vs baseline: 1.1114x; 1.1114x over previous
//
#include <hip/hip_runtime.h>
#include <math.h>

#define B_ 8
#define S_ 2
#define L_ 32000
#define T_ 497
#define AE 256
#define NFREQ 129
#define FC 385
#define XSTR 388
#define AFSTR 516
#define BTL 256
#define H_ 512
#define NB 32
#define EMBED 20
#define KB (T_*FC)
#define NPAIR 15
#define MEPS 1e-12f
#define PI2F 6.28318530717958647692f

// ---------------- workspace layout (floats) ----------------
static constexpr size_t ALGN(size_t x){ return (x + 63) & ~(size_t)63; }
static constexpr size_t o_mix  = 0;
static constexpr size_t o_dftB = ALGN(o_mix + (size_t)B_*L_);
static constexpr size_t o_spec = ALGN(o_dftB + (size_t)256*258);
static constexpr size_t o_enc  = ALGN(o_spec + (size_t)B_*T_*258);
static constexpr size_t o_mag  = ALGN(o_enc + (size_t)B_*T_*AE);
static constexpr size_t o_cosp = ALGN(o_mag + (size_t)B_*T_*NFREQ);
static constexpr size_t o_sinp = ALGN(o_cosp + (size_t)B_*T_*NFREQ);
static constexpr size_t o_xln  = ALGN(o_sinp + (size_t)B_*T_*NFREQ);
static constexpr size_t o_x    = ALGN(o_xln + (size_t)B_*T_*XSTR);
static constexpr size_t o_y    = ALGN(o_x + (size_t)B_*T_*BTL);
static constexpr size_t o_z    = ALGN(o_y + (size_t)B_*T_*H_);
static constexpr size_t o_gsum = ALGN(o_z + (size_t)B_*T_*H_);   // 32 blocks * 32 floats
static constexpr size_t o_acc  = o_gsum + 1024;                  // B*16*21 = 2688
static constexpr size_t o_att  = ALGN(o_acc + (size_t)B_*16*21);
static constexpr size_t o_decB = ALGN(o_att + (size_t)B_*2*EMBED);
static constexpr size_t o_decBias = ALGN(o_decB + (size_t)514*256);
static constexpr size_t o_emb  = ALGN(o_decBias + 256);
static constexpr size_t o_Af   = ALGN(o_emb + (size_t)B_*KB*EMBED); // 7952*516 floats
static constexpr size_t o_fr   = o_y;   // alias: ybuf dead before dec GEMM (same size)

// ---------------- small kernels ----------------
__global__ __launch_bounds__(256) void k_mix(const float* __restrict__ aud, float* __restrict__ mix){
  int i = blockIdx.x*256 + threadIdx.x;
  if (i < B_*L_){
    int b = i / L_, l = i % L_;
    mix[i] = aud[((size_t)b*S_+0)*L_ + l] + aud[((size_t)b*S_+1)*L_ + l];
  }
}

__global__ __launch_bounds__(256) void k_dftb(float* __restrict__ dftB){
  int i = blockIdx.x*256 + threadIdx.x;
  if (i < 256*258){
    int k = i / 258, n = i % 258;
    float win = sqrtf(0.5f - 0.5f*cosf(PI2F * (float)k / 256.0f));
    int f = (n < NFREQ) ? n : (n - NFREQ);
    int m = (k * f) & 255;
    float th = PI2F * (float)m / 256.0f;
    dftB[i] = (n < NFREQ) ? win * cosf(th) : -win * sinf(th);
  }
}

__global__ __launch_bounds__(256) void k_decb(const float* __restrict__ dec_w, const float* __restrict__ dec_b,
                                              float* __restrict__ decB, float* __restrict__ decBias){
  int i = blockIdx.x*256 + threadIdx.x;
  if (i < 514*256){
    int k = i / 256, n = i & 255;
    float v;
    if (k < 256){
      v = 0.5f * dec_w[(size_t)k*256 + n];
    } else {
      int m = n & 63;
      float den = 0.f;
      #pragma unroll
      for (int j = 0; j < 4; j++) den += 0.5f - 0.5f*cosf(PI2F*(float)(m + 64*j)/256.0f);
      float win = sqrtf(0.5f - 0.5f*cosf(PI2F*(float)n/256.0f));
      float iw = win / den;
      int f = (k < 385) ? (k - 256) : (k - 385);
      int mm = (f * n) & 255;
      float th = PI2F * (float)mm / 256.0f;
      if (k < 385){
        float cf = (f==0 || f==128) ? 1.0f : 2.0f;
        v = 0.5f * iw * cf * cosf(th) * (1.0f/256.0f);
      } else {
        v = (f==0 || f==128) ? 0.0f : -1.0f * iw * sinf(th) * (1.0f/256.0f); // 0.5*2
      }
    }
    decB[i] = v;
    if (i < 256) decBias[i] = 0.5f * dec_b[i];
  }
}

// ---------------- frames GEMM (A gathered from mix), K=256 ----------------
__global__ __launch_bounds__(256) void gemm_frames(
    const float* __restrict__ mix, const float* __restrict__ Bm,
    const float* __restrict__ bias, float* __restrict__ C, int N, int relu){
  const int M = B_*T_, K = 256;
  __shared__ float As[16][68];
  __shared__ float Bs[16][68];
  const int tid = threadIdx.x;
  const int tx = tid & 15, ty = tid >> 4;
  const int row0 = blockIdx.y*64, col0 = blockIdx.x*64;
  const int am = tid >> 2, ak = (tid & 3) * 4;
  const int bkk = tid >> 4, bn = (tid & 15) * 4;
  const int arow = row0 + am;
  const float* aptr = nullptr;
  if (arow < M){ int b = arow / T_, t = arow % T_; aptr = mix + (size_t)b*L_ + t*64; }
  float acc[4][4] = {};
  for (int k0 = 0; k0 < K; k0 += 16){
    #pragma unroll
    for (int i = 0; i < 4; i++)
      As[ak+i][am] = aptr ? aptr[k0+ak+i] : 0.f;
    #pragma unroll
    for (int i = 0; i < 4; i++){
      int n = col0 + bn + i;
      Bs[bkk][bn+i] = (n < N) ? Bm[(size_t)(k0+bkk)*N + n] : 0.f;
    }
    __syncthreads();
    #pragma unroll
    for (int kk = 0; kk < 16; kk++){
      float av[4], bv[4];
      #pragma unroll
      for (int i = 0; i < 4; i++) av[i] = As[kk][ty*4+i];
      #pragma unroll
      for (int j = 0; j < 4; j++) bv[j] = Bs[kk][tx*4+j];
      #pragma unroll
      for (int i = 0; i < 4; i++)
        #pragma unroll
        for (int j = 0; j < 4; j++) acc[i][j] = fmaf(av[i], bv[j], acc[i][j]);
    }
    __syncthreads();
  }
  #pragma unroll
  for (int i = 0; i < 4; i++){
    int r = row0 + ty*4 + i;
    if (r >= M) continue;
    #pragma unroll
    for (int j = 0; j < 4; j++){
      int c = col0 + tx*4 + j;
      if (c >= N) continue;
      float v = acc[i][j] + (bias ? bias[c] : 0.f);
      if (relu) v = fmaxf(v, 0.f);
      C[(size_t)r*N + c] = v;
    }
  }
}

// ---------------- 128x64 f32 GEMM ----------------
// ALOAD: 0 plain A, 1 gLN-affine on A load (aff_g, aff_b, gsumIn)
// EPI:   0 bias only, 1 bias+PReLU+store+partial sums (BUNIF grid), 2 bias+residual
template<int ALOAD, int EPI, bool BUNIF>
__global__ __launch_bounds__(256) void gemm2(
    const float* __restrict__ A, const float* __restrict__ Bm,
    const float* __restrict__ bias, float* __restrict__ C,
    int M, int N, int K, int lda,
    const float* __restrict__ aff_g, const float* __restrict__ aff_b,
    const float* __restrict__ gsumIn,
    const float* __restrict__ prelu_a, float* __restrict__ gsumOut,
    const float* __restrict__ resid)
{
  __shared__ float As[16][132];
  __shared__ float Bs[16][68];
  __shared__ float red[8];
  const int tid = threadIdx.x;
  const int tx = tid & 15, ty = tid >> 4;
  const int row0 = blockIdx.y * 128, col0 = blockIdx.x * 64;
  const int rbase = BUNIF ? (int)blockIdx.z * T_ : 0;
  const int am  = tid >> 2;        // 0..63
  const int akg = (tid & 3) * 4;   // k offset
  const int bk  = tid >> 4, bn = (tid & 15) * 4;

  const float* aptr[2]; bool aok[2];
  float amean[2] = {0.f, 0.f}, arstd[2] = {0.f, 0.f};
  #pragma unroll
  for (int i = 0; i < 2; i++){
    int r_l = row0 + am + 64*i;
    aok[i] = (r_l < M);
    int grow = rbase + (aok[i] ? r_l : 0);
    aptr[i] = A + (size_t)grow * lda;
    if (ALOAD == 1 && aok[i]){
      int b = grow / T_;
      float icnt = 1.0f / ((float)T_ * (float)K);
      float s = gsumIn[b*2], ss = gsumIn[b*2+1];
      amean[i] = s * icnt;
      arstd[i] = rsqrtf(ss * icnt - amean[i]*amean[i] + MEPS);
    }
  }
  const bool bfull = (col0 + 64 <= N);

  float acc[8][4] = {};
  const int ksteps = (K + 15) >> 4;
  for (int ks = 0; ks < ksteps; ks++){
    const int k0 = ks << 4;
    #pragma unroll
    for (int i = 0; i < 2; i++){
      float4 v = make_float4(0.f, 0.f, 0.f, 0.f);
      float* pv = (float*)&v;
      if (aok[i]){
        if (k0 + akg + 4 <= lda){
          v = *(const float4*)(aptr[i] + k0 + akg);
        } else {
          #pragma unroll
          for (int j = 0; j < 4; j++){ int k = k0+akg+j; if (k < K) pv[j] = aptr[i][k]; }
        }
        if (ALOAD == 1){
          #pragma unroll
          for (int j = 0; j < 4; j++){
            int k = k0+akg+j;
            if (k < K) pv[j] = (pv[j]-amean[i])*arstd[i]*aff_g[k] + aff_b[k];
            else pv[j] = 0.f;
          }
        }
      }
      #pragma unroll
      for (int j = 0; j < 4; j++) As[akg+j][am + 64*i] = pv[j];
    }
    {
      float4 v = make_float4(0.f, 0.f, 0.f, 0.f);
      float* pv = (float*)&v;
      int k = k0 + bk;
      if (k < K){
        if (bfull) v = *(const float4*)(Bm + (size_t)k*N + col0 + bn);
        else {
          #pragma unroll
          for (int j = 0; j < 4; j++){ int c = col0+bn+j; if (c < N) pv[j] = Bm[(size_t)k*N + c]; }
        }
      }
      *(float4*)&Bs[bk][bn] = v;
    }
    __syncthreads();
    #pragma unroll
    for (int kk = 0; kk < 16; kk++){
      float av[8], bv[4];
      #pragma unroll
      for (int i = 0; i < 8; i++) av[i] = As[kk][ty*8+i];
      #pragma unroll
      for (int j = 0; j < 4; j++) bv[j] = Bs[kk][tx*4+j];
      #pragma unroll
      for (int i = 0; i < 8; i++)
        #pragma unroll
        for (int j = 0; j < 4; j++) acc[i][j] = fmaf(av[i], bv[j], acc[i][j]);
    }
    __syncthreads();
  }
  // epilogue
  float bb[4], pa[4];
  #pragma unroll
  for (int j = 0; j < 4; j++){
    int c = col0 + tx*4 + j;
    bb[j] = (bias && c < N) ? bias[c] : 0.f;
    pa[j] = (EPI == 1 && c < N) ? prelu_a[c] : 0.f;
  }
  float ps = 0.f, pss = 0.f;
  #pragma unroll
  for (int i = 0; i < 8; i++){
    int r_l = row0 + ty*8 + i;
    if (r_l >= M) continue;
    size_t r_g = (size_t)(rbase + r_l);
    int c0 = col0 + tx*4;
    if (bfull){
      float4 o; float* po = (float*)&o;
      if (EPI == 2){
        float4 rv = *(const float4*)(resid + r_g*N + c0);
        float* pr = (float*)&rv;
        #pragma unroll
        for (int j = 0; j < 4; j++) po[j] = acc[i][j] + bb[j] + pr[j];
      } else if (EPI == 1){
        #pragma unroll
        for (int j = 0; j < 4; j++){
          float v = acc[i][j] + bb[j];
          float p = fmaxf(v, 0.f) + pa[j]*fminf(v, 0.f);
          po[j] = p; ps += p; pss += p*p;
        }
      } else {
        #pragma unroll
        for (int j = 0; j < 4; j++) po[j] = acc[i][j] + bb[j];
      }
      *(float4*)(C + r_g*N + c0) = o;
    } else {
      #pragma unroll
      for (int j = 0; j < 4; j++){
        int c = c0 + j;
        if (c >= N) continue;
        float v = acc[i][j] + bb[j];
        if (EPI == 1){
          float p = fmaxf(v, 0.f) + pa[j]*fminf(v, 0.f);
          C[r_g*N + c] = p; ps += p; pss += p*p;
        } else if (EPI == 2){
          C[r_g*N + c] = v + resid[r_g*N + c];
        } else {
          C[r_g*N + c] = v;
        }
      }
    }
  }
  if (EPI == 1){
    #pragma unroll
    for (int off = 32; off > 0; off >>= 1){
      ps  += __shfl_down(ps, off);
      pss += __shfl_down(pss, off);
    }
    if ((tid & 63) == 0){ red[(tid>>6)*2] = ps; red[(tid>>6)*2+1] = pss; }
    __syncthreads();
    if (tid == 0){
      atomicAdd(&gsumOut[blockIdx.z*2],     red[0]+red[2]+red[4]+red[6]);
      atomicAdd(&gsumOut[blockIdx.z*2 + 1], red[1]+red[3]+red[5]+red[7]);
    }
  }
}

// ---------------- cLN over [enc | log1p(mag)] ----------------
__global__ __launch_bounds__(256) void k_cln(
    const float* __restrict__ spec, const float* __restrict__ enc,
    const float* __restrict__ gamma, const float* __restrict__ beta,
    float* __restrict__ mag, float* __restrict__ cosp, float* __restrict__ sinp,
    float* __restrict__ xln){
  int t = blockIdx.x, b = blockIdx.y, tid = threadIdx.x;
  size_t row = (size_t)b*T_ + t;
  __shared__ float feat[FC];
  __shared__ float red[8];
  feat[tid] = enc[row*AE + tid];
  if (tid < NFREQ){
    float re = spec[row*258 + tid], im = spec[row*258 + NFREQ + tid];
    float m = sqrtf(re*re + im*im);
    mag[row*NFREQ + tid] = m;
    float c = 1.f, s = 0.f;
    if (m > 0.f){ c = re/m; s = im/m; }
    cosp[row*NFREQ + tid] = c;
    sinp[row*NFREQ + tid] = s;
    feat[AE + tid] = log1pf(m);
  }
  __syncthreads();
  float v = feat[tid] + ((tid < FC-256) ? feat[256+tid] : 0.f);
  #pragma unroll
  for (int off = 32; off > 0; off >>= 1) v += __shfl_down(v, off);
  if ((tid & 63) == 0) red[tid>>6] = v;
  __syncthreads();
  float mean = (red[0]+red[1]+red[2]+red[3]) * (1.0f/FC);
  float d0 = feat[tid] - mean;
  float vv = d0*d0;
  if (tid < FC-256){ float d1 = feat[256+tid] - mean; vv += d1*d1; }
  __syncthreads();
  #pragma unroll
  for (int off = 32; off > 0; off >>= 1) vv += __shfl_down(vv, off);
  if ((tid & 63) == 0) red[tid>>6] = vv;
  __syncthreads();
  float var = (red[0]+red[1]+red[2]+red[3]) * (1.0f/FC);
  float rstd = rsqrtf(var + MEPS);
  xln[row*XSTR + tid] = (feat[tid]-mean)*rstd*gamma[tid] + beta[tid];
  if (tid < FC-256)
    xln[row*XSTR + 256+tid] = (feat[256+tid]-mean)*rstd*gamma[256+tid] + beta[256+tid];
  if (tid < XSTR-FC) xln[row*XSTR + FC + tid] = 0.f;
}

// ---------------- dilated depthwise conv with gLN-affine on load ----------------
__global__ __launch_bounds__(256) void k_dwconv(
    const float* __restrict__ ybuf, const float* __restrict__ dw,
    const float* __restrict__ g1g, const float* __restrict__ g1b,
    const float* __restrict__ gsum1, const float* __restrict__ p2a,
    float* __restrict__ zbuf, float* __restrict__ gsum2, int dil){
  int t = blockIdx.x, b = blockIdx.y, tid = threadIdx.x;
  float icnt = 1.0f / ((float)T_ * (float)H_);
  float m = gsum1[b*2] * icnt;
  float var = gsum1[b*2+1] * icnt - m*m;
  float rstd = rsqrtf(var + MEPS);
  __shared__ float red[8];
  float ps = 0.f, pss = 0.f;
  for (int c = tid; c < H_; c += 256){
    float g = g1g[c] * rstd;
    float bb = g1b[c] - m * g;
    float z = 0.f;
    #pragma unroll
    for (int kk = 0; kk < 3; kk++){
      int tt = t + (kk-1)*dil;
      if (tt >= 0 && tt < T_){
        float p = ybuf[((size_t)b*T_ + tt)*H_ + c];
        z += dw[kk*H_ + c] * (p*g + bb);
      }
    }
    float p2 = fmaxf(z, 0.f) + p2a[c] * fminf(z, 0.f);
    zbuf[((size_t)b*T_ + t)*H_ + c] = p2;
    ps += p2; pss += p2*p2;
  }
  #pragma unroll
  for (int off = 32; off > 0; off >>= 1){
    ps  += __shfl_down(ps, off);
    pss += __shfl_down(pss, off);
  }
  if ((tid & 63) == 0){ red[(tid>>6)*2] = ps; red[(tid>>6)*2+1] = pss; }
  __syncthreads();
  if (tid == 0){
    float s  = red[0] + red[2] + red[4] + red[6];
    float ss = red[1] + red[3] + red[5] + red[7];
    atomicAdd(&gsum2[b*2],     s);
    atomicAdd(&gsum2[b*2 + 1], ss);
  }
}

// ---------------- attractor accumulation (register accumulators) ----------------
// blockIdx.y = b*4 + g; group g covers slots 4g..4g+3; slot<15 = pair (sigmoid
// weight), slot 15 = raw sums (weight 1). acc layout: [b][16][21].
#define ATTR_CH 16
__global__ __launch_bounds__(256) void k_attr2(const float* __restrict__ emb,
                                               const float* __restrict__ anchors,
                                               float* __restrict__ acc){
  const int c0a[16] = {0,0,0,0,0,1,1,1,1,2,2,2,3,3,4,0};
  const int c1a[16] = {1,2,3,4,5,2,3,4,5,3,4,5,4,5,5,0};
  int by = blockIdx.y;
  int b = by >> 2, g = by & 3;
  int tid = threadIdx.x;
  __shared__ float anc[6][20];
  __shared__ float wred[4][84];
  if (tid < 120) anc[tid/20][tid%20] = anchors[tid];
  __syncthreads();
  float ar[4][21];
  #pragma unroll
  for (int q = 0; q < 4; q++)
    #pragma unroll
    for (int e = 0; e < 21; e++) ar[q][e] = 0.f;
  const float* eb = emb + (size_t)b*KB*EMBED;
  for (int k = blockIdx.x*256 + tid; k < KB; k += ATTR_CH*256){
    float e[20];
    const float4* p = (const float4*)(eb + (size_t)k*EMBED);
    #pragma unroll
    for (int i = 0; i < 5; i++){
      float4 v = p[i];
      e[4*i] = v.x; e[4*i+1] = v.y; e[4*i+2] = v.z; e[4*i+3] = v.w;
    }
    float d[6];
    #pragma unroll
    for (int c = 0; c < 6; c++){
      float s = 0.f;
      #pragma unroll
      for (int j = 0; j < 20; j++) s = fmaf(e[j], anc[c][j], s);
      d[c] = s;
    }
    #pragma unroll
    for (int q = 0; q < 4; q++){
      int s = g*4 + q;
      float w = (s == 15) ? 1.0f : 1.0f / (1.0f + expf(d[c1a[s]] - d[c0a[s]]));
      #pragma unroll
      for (int j = 0; j < 20; j++) ar[q][j] = fmaf(w, e[j], ar[q][j]);
      ar[q][20] += w;
    }
  }
  // wave reduce
  #pragma unroll
  for (int q = 0; q < 4; q++)
    #pragma unroll
    for (int e = 0; e < 21; e++)
      #pragma unroll
      for (int off = 32; off > 0; off >>= 1)
        ar[q][e] += __shfl_down(ar[q][e], off);
  if ((tid & 63) == 0){
    int w = tid >> 6;
    #pragma unroll
    for (int q = 0; q < 4; q++)
      #pragma unroll
      for (int e = 0; e < 21; e++) wred[w][q*21+e] = ar[q][e];
  }
  __syncthreads();
  if (tid < 84){
    float s = wred[0][tid] + wred[1][tid] + wred[2][tid] + wred[3][tid];
    int q = tid / 21, e = tid % 21;
    atomicAdd(&acc[((size_t)b*16 + g*4 + q)*21 + e], s);
  }
}

// ---------------- attractor normalize + select ----------------
__global__ __launch_bounds__(128) void k_attrfin2(const float* __restrict__ acc,
                                                  float* __restrict__ attractors){
  __shared__ float aN[120][40];
  __shared__ float sp[120];
  int tid = threadIdx.x;
  if (tid < 120){
    int b = tid / 15, p = tid % 15;
    const float* ap = acc + ((size_t)b*16 + p)*21;
    const float* ae = acc + ((size_t)b*16 + 15)*21;
    float den0 = ap[20];
    float den1 = (float)KB - den0;
    float s = 0.f;
    for (int e = 0; e < 20; e++){
      float a0 = ap[e] / den0;
      float a1 = (ae[e] - ap[e]) / den1;
      aN[tid][e] = a0; aN[tid][20+e] = a1;
      s = fmaf(a0, a1, s);
    }
    sp[tid] = s;
  }
  __syncthreads();
  if (tid < B_){
    int base = tid * 15, best = 0;
    float bv = sp[base];
    for (int p = 1; p < 15; p++) if (sp[base+p] < bv){ bv = sp[base+p]; best = p; }
    for (int i = 0; i < 40; i++) attractors[tid*40 + i] = aN[base+best][i];
  }
}

// ---------------- build decoder-GEMM A rows (stride AFSTR=516, pads zeroed) ---
__global__ __launch_bounds__(256) void k_afull(
    const float* __restrict__ emb, const float* __restrict__ enc,
    const float* __restrict__ mag, const float* __restrict__ cosp,
    const float* __restrict__ sinp, const float* __restrict__ attractors,
    float* __restrict__ Af){
  int t = blockIdx.x, b = blockIdx.y, tid = threadIdx.x;
  __shared__ float att[40];
  if (tid < 40) att[tid] = attractors[b*40 + tid];
  __syncthreads();
  size_t row = (size_t)b*T_ + t;
  size_t r0 = ((size_t)(b*2+0)*T_ + t)*AFSTR;
  size_t r1 = ((size_t)(b*2+1)*T_ + t)*AFSTR;
  for (int f = tid; f < FC; f += 256){
    const float* e = emb + (row*FC + f)*20;
    float l0 = 0.f, l1 = 0.f;
    #pragma unroll
    for (int j = 0; j < 20; j++){
      float ev = e[j];
      l0 = fmaf(ev, att[j],    l0);
      l1 = fmaf(ev, att[20+j], l1);
    }
    if (f < AE){
      float ft = enc[row*AE + f];
      Af[r0 + f] = l0*ft;
      Af[r1 + f] = l1*ft;
    } else {
      int fi = f - AE;
      float ft = mag[row*NFREQ + fi];
      float c = cosp[row*NFREQ + fi], s = sinp[row*NFREQ + fi];
      float s0 = l0*ft, s1v = l1*ft;
      Af[r0 + 256 + fi] = c*s0;  Af[r0 + 385 + fi] = s*s0;
      Af[r1 + 256 + fi] = c*s1v; Af[r1 + 385 + fi] = s*s1v;
    }
  }
  if (tid < 2){
    Af[r0 + 514 + tid] = 0.f;
    Af[r1 + 514 + tid] = 0.f;
  }
}

// ---------------- overlap-add gather ----------------
__global__ __launch_bounds__(256) void k_ola(const float* __restrict__ frames,
                                             float* __restrict__ out){
  int i = blockIdx.x*256 + threadIdx.x;
  if (i < B_*2*L_){
    int bs = i / L_, l = i % L_;
    int t0 = l >> 6;
    float s = 0.f;
    #pragma unroll
    for (int j = 0; j < 4; j++){
      int t = t0 - j;
      if (t >= 0 && t < T_){
        int k = l - t*64;
        s += frames[((size_t)bs*T_ + t)*256 + k];
      }
    }
    out[i] = s;
  }
}

// ---------------- launcher ----------------
extern "C" void kernel_launch(void* const* d_in, const int* in_sizes, int n_in,
                              void* d_out, int out_size, void* d_ws, size_t ws_size,
                              hipStream_t stream) {
  const float* audios   = (const float*)d_in[0];
  const float* enc_w    = (const float*)d_in[1];
  const float* enc_b    = (const float*)d_in[2];
  const float* bgamma   = (const float*)d_in[3];
  const float* bbeta    = (const float*)d_in[4];
  const float* bottle_w = (const float*)d_in[5];
  const float* bottle_b = (const float*)d_in[6];
  const float* c1_w     = (const float*)d_in[7];
  const float* c1_b     = (const float*)d_in[8];
  const float* p1       = (const float*)d_in[9];
  const float* g1_g     = (const float*)d_in[10];
  const float* g1_b     = (const float*)d_in[11];
  const float* dwp      = (const float*)d_in[12];
  const float* p2       = (const float*)d_in[13];
  const float* g2_g     = (const float*)d_in[14];
  const float* g2_b     = (const float*)d_in[15];
  const float* c2_w     = (const float*)d_in[16];
  const float* c2_b     = (const float*)d_in[17];
  const float* sep_w    = (const float*)d_in[18];
  const float* sep_b    = (const float*)d_in[19];
  const float* anchors  = (const float*)d_in[20];
  const float* dec_w    = (const float*)d_in[21];
  const float* dec_b    = (const float*)d_in[22];

  float* ws = (float*)d_ws;
  float* mix   = ws + o_mix;
  float* dftB  = ws + o_dftB;
  float* spec  = ws + o_spec;
  float* enc   = ws + o_enc;
  float* mag   = ws + o_mag;
  float* cosp  = ws + o_cosp;
  float* sinp  = ws + o_sinp;
  float* xln   = ws + o_xln;
  float* xbuf  = ws + o_x;
  float* ybuf  = ws + o_y;
  float* zbuf  = ws + o_z;
  float* gsum  = ws + o_gsum;
  float* accp  = ws + o_acc;
  float* attp  = ws + o_att;
  float* decB  = ws + o_decB;
  float* decBias = ws + o_decBias;
  float* embp  = ws + o_emb;
  float* Afull = ws + o_Af;
  float* framesp = ws + o_fr;

  // zero atomic accumulators (gsum 1024 + attr acc 2688, contiguous)
  hipMemsetAsync((void*)gsum, 0, (1024 + (size_t)B_*16*21) * sizeof(float), stream);

  k_mix <<<(B_*L_ + 255)/256, 256, 0, stream>>>(audios, mix);
  k_dftb<<<(256*258 + 255)/256, 256, 0, stream>>>(dftB);
  k_decb<<<(514*256 + 255)/256, 256, 0, stream>>>(dec_w, dec_b, decB, decBias);

  // encoder + spectrum
  gemm_frames<<<dim3(4, 63), 256, 0, stream>>>(mix, enc_w, enc_b, enc, 256, 1);
  gemm_frames<<<dim3(5, 63), 256, 0, stream>>>(mix, dftB, nullptr, spec, 258, 0);

  k_cln<<<dim3(T_, B_), 256, 0, stream>>>(spec, enc, bgamma, bbeta, mag, cosp, sinp, xln);

  // bottleneck: M=3976, N=256, K=385 (lda=388, zero-padded)
  gemm2<0,0,false><<<dim3(4, 32), 256, 0, stream>>>(
      xln, bottle_w, bottle_b, xbuf, B_*T_, BTL, FC, XSTR,
      nullptr, nullptr, nullptr, nullptr, nullptr, nullptr);

  // TCN
  for (int i = 0; i < NB; i++){
    int dil = 1 << (i & 7);
    gemm2<0,1,true><<<dim3(8, 4, B_), 256, 0, stream>>>(
        xbuf, c1_w + (size_t)i*BTL*H_, c1_b + i*H_, ybuf, T_, H_, BTL, BTL,
        nullptr, nullptr, nullptr, p1 + i*H_, gsum + i*32, nullptr);
    k_dwconv<<<dim3(T_, B_), 256, 0, stream>>>(
        ybuf, dwp + (size_t)i*3*H_, g1_g + i*H_, g1_b + i*H_,
        gsum + i*32, p2 + i*H_, zbuf, gsum + i*32 + 16, dil);
    gemm2<1,2,false><<<dim3(4, 32), 256, 0, stream>>>(
        zbuf, c2_w + (size_t)i*H_*BTL, c2_b + i*BTL, xbuf, B_*T_, BTL, H_, H_,
        g2_g + i*H_, g2_b + i*H_, gsum + i*32 + 16, nullptr, nullptr, xbuf);
  }

  // separator: M=3976, N=7700, K=256
  gemm2<0,0,false><<<dim3(121, 32), 256, 0, stream>>>(
      xbuf, sep_w, sep_b, embp, B_*T_, FC*EMBED, BTL, BTL,
      nullptr, nullptr, nullptr, nullptr, nullptr, nullptr);

  // attractors
  k_attr2<<<dim3(ATTR_CH, B_*4), 256, 0, stream>>>(embp, anchors, accp);
  k_attrfin2<<<1, 128, 0, stream>>>(accp, attp);

  // decode: M=7952, N=256, K=514 (lda=516, zero-padded)
  k_afull<<<dim3(T_, B_), 256, 0, stream>>>(embp, enc, mag, cosp, sinp, attp, Afull);
  gemm2<0,0,false><<<dim3(4, 63), 256, 0, stream>>>(
      Afull, decB, decBias, framesp, 2*B_*T_, 256, 514, AFSTR,
      nullptr, nullptr, nullptr, nullptr, nullptr, nullptr);
  k_ola<<<(B_*2*L_ + 255)/256, 256, 0, stream>>>(framesp, (float*)d_out);
}

// Round 6
// 5909.226 us; speedup vs baseline: 1.4667x; 1.3197x over previous
//
#include <hip/hip_runtime.h>
#include <math.h>

#define B_ 8
#define S_ 2
#define L_ 32000
#define T_ 497
#define AE 256
#define NFREQ 129
#define FC 385
#define XSTR 388
#define FRSTR 516
#define AFSTR 516
#define BTL 256
#define H_ 512
#define NB 32
#define EMBED 20
#define KB (T_*FC)
#define MEPS 1e-12f
#define PI2F 6.28318530717958647692f

// ---------------- workspace layout (floats) ----------------
static constexpr size_t ALGN(size_t x){ return (x + 63) & ~(size_t)63; }
static constexpr size_t o_bfr  = 0;                                   // 256*516
static constexpr size_t o_decB = ALGN(o_bfr + (size_t)256*516);       // 514*256
static constexpr size_t o_decBias = ALGN(o_decB + (size_t)514*256);   // 256
static constexpr size_t o_biasF  = ALGN(o_decBias + 256);             // 516
static constexpr size_t o_cf   = ALGN(o_biasF + 516);                 // 3976*516
static constexpr size_t o_mag  = ALGN(o_cf + (size_t)B_*T_*FRSTR);
static constexpr size_t o_cosp = ALGN(o_mag + (size_t)B_*T_*NFREQ);
static constexpr size_t o_sinp = ALGN(o_cosp + (size_t)B_*T_*NFREQ);
static constexpr size_t o_xln  = ALGN(o_sinp + (size_t)B_*T_*NFREQ);
static constexpr size_t o_x    = ALGN(o_xln + (size_t)B_*T_*XSTR);
static constexpr size_t o_y    = ALGN(o_x + (size_t)B_*T_*BTL);
static constexpr size_t o_z    = ALGN(o_y + (size_t)B_*T_*H_);
static constexpr size_t o_gsum = ALGN(o_z + (size_t)B_*T_*H_);   // 32 blocks * 32 floats
static constexpr size_t o_acc  = o_gsum + 1024;                  // B*16*21 = 2688
static constexpr size_t o_att  = ALGN(o_acc + (size_t)B_*16*21);
static constexpr size_t o_emb  = ALGN(o_att + (size_t)B_*2*EMBED);
static constexpr size_t o_Af   = ALGN(o_emb + (size_t)B_*KB*EMBED);  // 7952*516
static constexpr size_t o_fr   = o_y;   // alias: ybuf dead before dec GEMM (same size)

// ---------------- setup: combined frame-basis, decoder basis, biases --------
__global__ __launch_bounds__(256) void k_prep(const float* __restrict__ enc_w,
                                              const float* __restrict__ enc_b,
                                              const float* __restrict__ dec_w,
                                              const float* __restrict__ dec_b,
                                              float* __restrict__ bfr,
                                              float* __restrict__ decB,
                                              float* __restrict__ decBias,
                                              float* __restrict__ biasF){
  int i = blockIdx.x*256 + threadIdx.x;
  if (i < 256*516){
    int k = i / 516, n = i % 516;
    float v;
    if (n < 256) v = enc_w[(size_t)k*256 + n];
    else if (n < 514){
      int f2 = n - 256;
      float win = sqrtf(0.5f - 0.5f*cosf(PI2F * (float)k / 256.0f));
      int f = (f2 < NFREQ) ? f2 : (f2 - NFREQ);
      int m = (k * f) & 255;
      float th = PI2F * (float)m / 256.0f;
      v = (f2 < NFREQ) ? win * cosf(th) : -win * sinf(th);
    } else v = 0.f;
    bfr[i] = v;
    return;
  }
  int j = i - 256*516;
  if (j < 514*256){
    int k = j / 256, n = j & 255;
    float v;
    if (k < 256){
      v = 0.5f * dec_w[(size_t)k*256 + n];
    } else {
      int m = n & 63;
      float den = 0.f;
      #pragma unroll
      for (int q = 0; q < 4; q++) den += 0.5f - 0.5f*cosf(PI2F*(float)(m + 64*q)/256.0f);
      float win = sqrtf(0.5f - 0.5f*cosf(PI2F*(float)n/256.0f));
      float iw = win / den;
      int f = (k < 385) ? (k - 256) : (k - 385);
      int mm = (f * n) & 255;
      float th = PI2F * (float)mm / 256.0f;
      if (k < 385){
        float cf = (f==0 || f==128) ? 1.0f : 2.0f;
        v = 0.5f * iw * cf * cosf(th) * (1.0f/256.0f);
      } else {
        v = (f==0 || f==128) ? 0.0f : -1.0f * iw * sinf(th) * (1.0f/256.0f);
      }
    }
    decB[j] = v;
    return;
  }
  int jj = j - 514*256;
  if (jj < 256){ decBias[jj] = 0.5f * dec_b[jj]; return; }
  int n = jj - 256;
  if (n < 516) biasF[n] = (n < 256) ? enc_b[n] : 0.f;
}

// ---------------- pipelined 64x64 GEMM ----------------
// ALOAD: 0 plain A; 1 gLN-affine on A load; 2 A = summed audio frames
// EPI:   0 bias (+relu for c<relu_cols); 1 bias+PReLU+partial sums (BUNIF); 2 bias+residual
template<int ALOAD, int EPI, bool BUNIF>
__global__ __launch_bounds__(256, 2) void gemm3(
    const float* __restrict__ A, const float* __restrict__ Bm,
    const float* __restrict__ bias, float* __restrict__ C,
    int M, int N, int K, int lda, int ldb,
    const float* __restrict__ aff_g, const float* __restrict__ aff_b,
    const float* __restrict__ gsumIn,
    const float* __restrict__ prelu_a, float* __restrict__ gsumOut,
    const float* __restrict__ resid, int relu_cols)
{
  __shared__ float As[16][68];
  __shared__ float Bs[16][68];
  __shared__ float red[8];
  const int tid = threadIdx.x;
  const int tx = tid & 15, ty = tid >> 4;
  const int row0 = blockIdx.y*64, col0 = blockIdx.x*64;
  const int rbase = BUNIF ? (int)blockIdx.z*T_ : 0;
  const int am = tid >> 2, ak = (tid & 3)*4;
  const int bk = tid >> 4, bn = (tid & 15)*4;
  const int arow = row0 + am;
  const bool aok = arow < M;
  const float* aptr = nullptr;
  const float* ap0 = nullptr; const float* ap1 = nullptr;
  if (ALOAD == 2){
    int r = aok ? arow : 0;
    int b = r / T_, t = r % T_;
    ap0 = A + ((size_t)b*2)*L_ + t*64;
    ap1 = ap0 + L_;
  } else {
    aptr = A + (size_t)(rbase + (aok ? arow : 0))*lda;
  }
  float amean = 0.f, arstd = 0.f;
  if (ALOAD == 1){
    int b = (rbase + (aok ? arow : 0)) / T_;
    float icnt = 1.f/((float)T_*(float)K);
    amean = gsumIn[b*2]*icnt;
    arstd = rsqrtf(gsumIn[b*2+1]*icnt - amean*amean + MEPS);
  }
  const bool bfull = (col0 + 64 <= N);
  const int ksteps = (K+15) >> 4;

  float4 av, bv, ag, ab;
  ag = make_float4(0,0,0,0); ab = ag;

#define LOADA(ks_) { int k0 = (ks_) << 4; \
    av = make_float4(0.f,0.f,0.f,0.f); \
    if (aok){ \
      if (ALOAD == 2){ \
        float4 u = *(const float4*)(ap0 + k0 + ak); \
        float4 w = *(const float4*)(ap1 + k0 + ak); \
        av.x = u.x+w.x; av.y = u.y+w.y; av.z = u.z+w.z; av.w = u.w+w.w; \
      } else if (k0 + ak + 4 <= lda){ \
        av = *(const float4*)(aptr + k0 + ak); \
      } else { \
        float* pv = (float*)&av; \
        for (int j = 0; j < 4; j++){ int k = k0+ak+j; if (k < K) pv[j] = aptr[k]; } \
      } \
    } \
    if (ALOAD == 1){ ag = *(const float4*)(aff_g + k0 + ak); ab = *(const float4*)(aff_b + k0 + ak); } }

#define LOADB(ks_) { int k = ((ks_) << 4) + bk; \
    bv = make_float4(0.f,0.f,0.f,0.f); \
    if (k < K){ \
      if (bfull) bv = *(const float4*)(Bm + (size_t)k*ldb + col0 + bn); \
      else { float* pv = (float*)&bv; \
        for (int j = 0; j < 4; j++){ int c = col0+bn+j; if (c < N) pv[j] = Bm[(size_t)k*ldb + c]; } } } }

  float acc[4][4] = {};
  LOADA(0); LOADB(0);
  for (int ks = 0; ks < ksteps; ks++){
    float4 aw = av;
    if (ALOAD == 1){
      aw.x = (aw.x-amean)*arstd*ag.x + ab.x;
      aw.y = (aw.y-amean)*arstd*ag.y + ab.y;
      aw.z = (aw.z-amean)*arstd*ag.z + ab.z;
      aw.w = (aw.w-amean)*arstd*ag.w + ab.w;
    }
    As[ak+0][am] = aw.x; As[ak+1][am] = aw.y;
    As[ak+2][am] = aw.z; As[ak+3][am] = aw.w;
    *(float4*)&Bs[bk][bn] = bv;
    __syncthreads();
    if (ks + 1 < ksteps){ LOADA(ks+1); LOADB(ks+1); }
    #pragma unroll
    for (int kk = 0; kk < 16; kk++){
      float a4[4], b4[4];
      *(float4*)a4 = *(const float4*)&As[kk][ty*4];
      *(float4*)b4 = *(const float4*)&Bs[kk][tx*4];
      #pragma unroll
      for (int i = 0; i < 4; i++)
        #pragma unroll
        for (int j = 0; j < 4; j++) acc[i][j] = fmaf(a4[i], b4[j], acc[i][j]);
    }
    __syncthreads();
  }
#undef LOADA
#undef LOADB

  float bb4[4], pa4[4];
  #pragma unroll
  for (int j = 0; j < 4; j++){
    int c = col0 + tx*4 + j;
    bb4[j] = (bias && c < N) ? bias[c] : 0.f;
    pa4[j] = (EPI == 1 && c < N) ? prelu_a[c] : 0.f;
  }
  float ps = 0.f, pss = 0.f;
  #pragma unroll
  for (int i = 0; i < 4; i++){
    int r_l = row0 + ty*4 + i;
    if (r_l >= M) continue;
    size_t r_g = (size_t)(rbase + r_l);
    int c0 = col0 + tx*4;
    if (bfull){
      float4 o; float* po = (float*)&o;
      if (EPI == 2){
        float4 rv = *(const float4*)(resid + r_g*N + c0); float* pr = (float*)&rv;
        #pragma unroll
        for (int j = 0; j < 4; j++) po[j] = acc[i][j] + bb4[j] + pr[j];
      } else if (EPI == 1){
        #pragma unroll
        for (int j = 0; j < 4; j++){
          float v = acc[i][j] + bb4[j];
          float p = fmaxf(v, 0.f) + pa4[j]*fminf(v, 0.f);
          po[j] = p; ps += p; pss += p*p;
        }
      } else {
        #pragma unroll
        for (int j = 0; j < 4; j++){
          float v = acc[i][j] + bb4[j];
          if (c0 + j < relu_cols) v = fmaxf(v, 0.f);
          po[j] = v;
        }
      }
      *(float4*)(C + r_g*N + c0) = o;
    } else {
      #pragma unroll
      for (int j = 0; j < 4; j++){
        int c = c0 + j;
        if (c >= N) continue;
        float v = acc[i][j] + bb4[j];
        if (EPI == 1){
          float p = fmaxf(v, 0.f) + pa4[j]*fminf(v, 0.f);
          C[r_g*N + c] = p; ps += p; pss += p*p;
        } else if (EPI == 2){
          C[r_g*N + c] = v + resid[r_g*N + c];
        } else {
          if (c < relu_cols) v = fmaxf(v, 0.f);
          C[r_g*N + c] = v;
        }
      }
    }
  }
  if (EPI == 1){
    #pragma unroll
    for (int off = 32; off > 0; off >>= 1){
      ps  += __shfl_down(ps, off);
      pss += __shfl_down(pss, off);
    }
    if ((tid & 63) == 0){ red[(tid>>6)*2] = ps; red[(tid>>6)*2+1] = pss; }
    __syncthreads();
    if (tid == 0){
      atomicAdd(&gsumOut[blockIdx.z*2],     red[0]+red[2]+red[4]+red[6]);
      atomicAdd(&gsumOut[blockIdx.z*2 + 1], red[1]+red[3]+red[5]+red[7]);
    }
  }
}

// ---------------- 128x64 f32 GEMM (separator only, unchanged from R2) -------
template<int ALOAD, int EPI, bool BUNIF>
__global__ __launch_bounds__(256) void gemm2(
    const float* __restrict__ A, const float* __restrict__ Bm,
    const float* __restrict__ bias, float* __restrict__ C,
    int M, int N, int K, int lda,
    const float* __restrict__ aff_g, const float* __restrict__ aff_b,
    const float* __restrict__ gsumIn,
    const float* __restrict__ prelu_a, float* __restrict__ gsumOut,
    const float* __restrict__ resid)
{
  __shared__ float As[16][132];
  __shared__ float Bs[16][68];
  const int tid = threadIdx.x;
  const int tx = tid & 15, ty = tid >> 4;
  const int row0 = blockIdx.y * 128, col0 = blockIdx.x * 64;
  const int am  = tid >> 2;
  const int akg = (tid & 3) * 4;
  const int bk  = tid >> 4, bn = (tid & 15) * 4;

  const float* aptr[2]; bool aok[2];
  #pragma unroll
  for (int i = 0; i < 2; i++){
    int r_l = row0 + am + 64*i;
    aok[i] = (r_l < M);
    aptr[i] = A + (size_t)(aok[i] ? r_l : 0) * lda;
  }
  const bool bfull = (col0 + 64 <= N);

  float acc[8][4] = {};
  const int ksteps = (K + 15) >> 4;
  for (int ks = 0; ks < ksteps; ks++){
    const int k0 = ks << 4;
    #pragma unroll
    for (int i = 0; i < 2; i++){
      float4 v = make_float4(0.f, 0.f, 0.f, 0.f);
      float* pv = (float*)&v;
      if (aok[i]){
        if (k0 + akg + 4 <= lda) v = *(const float4*)(aptr[i] + k0 + akg);
        else {
          #pragma unroll
          for (int j = 0; j < 4; j++){ int k = k0+akg+j; if (k < K) pv[j] = aptr[i][k]; }
        }
      }
      #pragma unroll
      for (int j = 0; j < 4; j++) As[akg+j][am + 64*i] = pv[j];
    }
    {
      float4 v = make_float4(0.f, 0.f, 0.f, 0.f);
      float* pv = (float*)&v;
      int k = k0 + bk;
      if (k < K){
        if (bfull) v = *(const float4*)(Bm + (size_t)k*N + col0 + bn);
        else {
          #pragma unroll
          for (int j = 0; j < 4; j++){ int c = col0+bn+j; if (c < N) pv[j] = Bm[(size_t)k*N + c]; }
        }
      }
      *(float4*)&Bs[bk][bn] = v;
    }
    __syncthreads();
    #pragma unroll
    for (int kk = 0; kk < 16; kk++){
      float av[8], bv[4];
      #pragma unroll
      for (int i = 0; i < 8; i++) av[i] = As[kk][ty*8+i];
      #pragma unroll
      for (int j = 0; j < 4; j++) bv[j] = Bs[kk][tx*4+j];
      #pragma unroll
      for (int i = 0; i < 8; i++)
        #pragma unroll
        for (int j = 0; j < 4; j++) acc[i][j] = fmaf(av[i], bv[j], acc[i][j]);
    }
    __syncthreads();
  }
  float bb[4];
  #pragma unroll
  for (int j = 0; j < 4; j++){
    int c = col0 + tx*4 + j;
    bb[j] = (bias && c < N) ? bias[c] : 0.f;
  }
  #pragma unroll
  for (int i = 0; i < 8; i++){
    int r_l = row0 + ty*8 + i;
    if (r_l >= M) continue;
    size_t r_g = (size_t)r_l;
    int c0 = col0 + tx*4;
    if (bfull){
      float4 o; float* po = (float*)&o;
      #pragma unroll
      for (int j = 0; j < 4; j++) po[j] = acc[i][j] + bb[j];
      *(float4*)(C + r_g*N + c0) = o;
    } else {
      #pragma unroll
      for (int j = 0; j < 4; j++){
        int c = c0 + j;
        if (c >= N) continue;
        C[r_g*N + c] = acc[i][j] + bb[j];
      }
    }
  }
}

// ---------------- cLN over [enc | log1p(mag)] ----------------
__global__ __launch_bounds__(256) void k_cln(
    const float* __restrict__ cf,
    const float* __restrict__ gamma, const float* __restrict__ beta,
    float* __restrict__ mag, float* __restrict__ cosp, float* __restrict__ sinp,
    float* __restrict__ xln){
  int t = blockIdx.x, b = blockIdx.y, tid = threadIdx.x;
  size_t row = (size_t)b*T_ + t;
  __shared__ float feat[FC];
  __shared__ float red[8];
  feat[tid] = cf[row*FRSTR + tid];
  if (tid < NFREQ){
    float re = cf[row*FRSTR + 256 + tid], im = cf[row*FRSTR + 385 + tid];
    float m = sqrtf(re*re + im*im);
    mag[row*NFREQ + tid] = m;
    float c = 1.f, s = 0.f;
    if (m > 0.f){ c = re/m; s = im/m; }
    cosp[row*NFREQ + tid] = c;
    sinp[row*NFREQ + tid] = s;
    feat[AE + tid] = log1pf(m);
  }
  __syncthreads();
  float v = feat[tid] + ((tid < FC-256) ? feat[256+tid] : 0.f);
  #pragma unroll
  for (int off = 32; off > 0; off >>= 1) v += __shfl_down(v, off);
  if ((tid & 63) == 0) red[tid>>6] = v;
  __syncthreads();
  float mean = (red[0]+red[1]+red[2]+red[3]) * (1.0f/FC);
  float d0 = feat[tid] - mean;
  float vv = d0*d0;
  if (tid < FC-256){ float d1 = feat[256+tid] - mean; vv += d1*d1; }
  __syncthreads();
  #pragma unroll
  for (int off = 32; off > 0; off >>= 1) vv += __shfl_down(vv, off);
  if ((tid & 63) == 0) red[tid>>6] = vv;
  __syncthreads();
  float var = (red[0]+red[1]+red[2]+red[3]) * (1.0f/FC);
  float rstd = rsqrtf(var + MEPS);
  xln[row*XSTR + tid] = (feat[tid]-mean)*rstd*gamma[tid] + beta[tid];
  if (tid < FC-256)
    xln[row*XSTR + 256+tid] = (feat[256+tid]-mean)*rstd*gamma[256+tid] + beta[256+tid];
  if (tid < XSTR-FC) xln[row*XSTR + FC + tid] = 0.f;
}

// ---------------- dilated depthwise conv with gLN-affine on load ------------
__global__ __launch_bounds__(256) void k_dwconv(
    const float* __restrict__ ybuf, const float* __restrict__ dw,
    const float* __restrict__ g1g, const float* __restrict__ g1b,
    const float* __restrict__ gsum1, const float* __restrict__ p2a,
    float* __restrict__ zbuf, float* __restrict__ gsum2, int dil){
  int t = blockIdx.x, b = blockIdx.y, tid = threadIdx.x;
  float icnt = 1.0f / ((float)T_ * (float)H_);
  float m = gsum1[b*2] * icnt;
  float var = gsum1[b*2+1] * icnt - m*m;
  float rstd = rsqrtf(var + MEPS);
  __shared__ float red[8];
  float ps = 0.f, pss = 0.f;
  for (int c = tid; c < H_; c += 256){
    float g = g1g[c] * rstd;
    float bb = g1b[c] - m * g;
    float z = 0.f;
    #pragma unroll
    for (int kk = 0; kk < 3; kk++){
      int tt = t + (kk-1)*dil;
      if (tt >= 0 && tt < T_){
        float p = ybuf[((size_t)b*T_ + tt)*H_ + c];
        z += dw[kk*H_ + c] * (p*g + bb);
      }
    }
    float p2 = fmaxf(z, 0.f) + p2a[c] * fminf(z, 0.f);
    zbuf[((size_t)b*T_ + t)*H_ + c] = p2;
    ps += p2; pss += p2*p2;
  }
  #pragma unroll
  for (int off = 32; off > 0; off >>= 1){
    ps  += __shfl_down(ps, off);
    pss += __shfl_down(pss, off);
  }
  if ((tid & 63) == 0){ red[(tid>>6)*2] = ps; red[(tid>>6)*2+1] = pss; }
  __syncthreads();
  if (tid == 0){
    float s  = red[0] + red[2] + red[4] + red[6];
    float ss = red[1] + red[3] + red[5] + red[7];
    atomicAdd(&gsum2[b*2],     s);
    atomicAdd(&gsum2[b*2 + 1], ss);
  }
}

// ---------------- attractor accumulation (register accumulators) ------------
#define ATTR_CH 16
__global__ __launch_bounds__(256) void k_attr2(const float* __restrict__ emb,
                                               const float* __restrict__ anchors,
                                               float* __restrict__ acc){
  const int c0a[16] = {0,0,0,0,0,1,1,1,1,2,2,2,3,3,4,0};
  const int c1a[16] = {1,2,3,4,5,2,3,4,5,3,4,5,4,5,5,0};
  int by = blockIdx.y;
  int b = by >> 2, g = by & 3;
  int tid = threadIdx.x;
  __shared__ float anc[6][20];
  __shared__ float wred[4][84];
  if (tid < 120) anc[tid/20][tid%20] = anchors[tid];
  __syncthreads();
  float ar[4][21];
  #pragma unroll
  for (int q = 0; q < 4; q++)
    #pragma unroll
    for (int e = 0; e < 21; e++) ar[q][e] = 0.f;
  const float* eb = emb + (size_t)b*KB*EMBED;
  for (int k = blockIdx.x*256 + tid; k < KB; k += ATTR_CH*256){
    float e[20];
    const float4* p = (const float4*)(eb + (size_t)k*EMBED);
    #pragma unroll
    for (int i = 0; i < 5; i++){
      float4 v = p[i];
      e[4*i] = v.x; e[4*i+1] = v.y; e[4*i+2] = v.z; e[4*i+3] = v.w;
    }
    float d[6];
    #pragma unroll
    for (int c = 0; c < 6; c++){
      float s = 0.f;
      #pragma unroll
      for (int j = 0; j < 20; j++) s = fmaf(e[j], anc[c][j], s);
      d[c] = s;
    }
    #pragma unroll
    for (int q = 0; q < 4; q++){
      int s = g*4 + q;
      float w = (s == 15) ? 1.0f : 1.0f / (1.0f + expf(d[c1a[s]] - d[c0a[s]]));
      #pragma unroll
      for (int j = 0; j < 20; j++) ar[q][j] = fmaf(w, e[j], ar[q][j]);
      ar[q][20] += w;
    }
  }
  #pragma unroll
  for (int q = 0; q < 4; q++)
    #pragma unroll
    for (int e = 0; e < 21; e++)
      #pragma unroll
      for (int off = 32; off > 0; off >>= 1)
        ar[q][e] += __shfl_down(ar[q][e], off);
  if ((tid & 63) == 0){
    int w = tid >> 6;
    #pragma unroll
    for (int q = 0; q < 4; q++)
      #pragma unroll
      for (int e = 0; e < 21; e++) wred[w][q*21+e] = ar[q][e];
  }
  __syncthreads();
  if (tid < 84){
    float s = wred[0][tid] + wred[1][tid] + wred[2][tid] + wred[3][tid];
    int q = tid / 21, e = tid % 21;
    atomicAdd(&acc[((size_t)b*16 + g*4 + q)*21 + e], s);
  }
}

// ---------------- attractor normalize + select ----------------
__global__ __launch_bounds__(128) void k_attrfin2(const float* __restrict__ acc,
                                                  float* __restrict__ attractors){
  __shared__ float aN[120][40];
  __shared__ float sp[120];
  int tid = threadIdx.x;
  if (tid < 120){
    int b = tid / 15, p = tid % 15;
    const float* ap = acc + ((size_t)b*16 + p)*21;
    const float* ae = acc + ((size_t)b*16 + 15)*21;
    float den0 = ap[20];
    float den1 = (float)KB - den0;
    float s = 0.f;
    for (int e = 0; e < 20; e++){
      float a0 = ap[e] / den0;
      float a1 = (ae[e] - ap[e]) / den1;
      aN[tid][e] = a0; aN[tid][20+e] = a1;
      s = fmaf(a0, a1, s);
    }
    sp[tid] = s;
  }
  __syncthreads();
  if (tid < B_){
    int base = tid * 15, best = 0;
    float bv = sp[base];
    for (int p = 1; p < 15; p++) if (sp[base+p] < bv){ bv = sp[base+p]; best = p; }
    for (int i = 0; i < 40; i++) attractors[tid*40 + i] = aN[base+best][i];
  }
}

// ---------------- build decoder-GEMM A rows (stride 516, pads zeroed) -------
__global__ __launch_bounds__(256) void k_afull(
    const float* __restrict__ emb, const float* __restrict__ cf,
    const float* __restrict__ mag, const float* __restrict__ cosp,
    const float* __restrict__ sinp, const float* __restrict__ attractors,
    float* __restrict__ Af){
  int t = blockIdx.x, b = blockIdx.y, tid = threadIdx.x;
  __shared__ float att[40];
  if (tid < 40) att[tid] = attractors[b*40 + tid];
  __syncthreads();
  size_t row = (size_t)b*T_ + t;
  size_t r0 = ((size_t)(b*2+0)*T_ + t)*AFSTR;
  size_t r1 = ((size_t)(b*2+1)*T_ + t)*AFSTR;
  for (int f = tid; f < FC; f += 256){
    const float* e = emb + (row*FC + f)*20;
    float l0 = 0.f, l1 = 0.f;
    #pragma unroll
    for (int j = 0; j < 20; j++){
      float ev = e[j];
      l0 = fmaf(ev, att[j],    l0);
      l1 = fmaf(ev, att[20+j], l1);
    }
    if (f < AE){
      float ft = cf[row*FRSTR + f];
      Af[r0 + f] = l0*ft;
      Af[r1 + f] = l1*ft;
    } else {
      int fi = f - AE;
      float ft = mag[row*NFREQ + fi];
      float c = cosp[row*NFREQ + fi], s = sinp[row*NFREQ + fi];
      float s0 = l0*ft, s1v = l1*ft;
      Af[r0 + 256 + fi] = c*s0;  Af[r0 + 385 + fi] = s*s0;
      Af[r1 + 256 + fi] = c*s1v; Af[r1 + 385 + fi] = s*s1v;
    }
  }
  if (tid < 2){
    Af[r0 + 514 + tid] = 0.f;
    Af[r1 + 514 + tid] = 0.f;
  }
}

// ---------------- overlap-add gather ----------------
__global__ __launch_bounds__(256) void k_ola(const float* __restrict__ frames,
                                             float* __restrict__ out){
  int i = blockIdx.x*256 + threadIdx.x;
  if (i < B_*2*L_){
    int bs = i / L_, l = i % L_;
    int t0 = l >> 6;
    float s = 0.f;
    #pragma unroll
    for (int j = 0; j < 4; j++){
      int t = t0 - j;
      if (t >= 0 && t < T_){
        int k = l - t*64;
        s += frames[((size_t)bs*T_ + t)*256 + k];
      }
    }
    out[i] = s;
  }
}

// ---------------- launcher ----------------
extern "C" void kernel_launch(void* const* d_in, const int* in_sizes, int n_in,
                              void* d_out, int out_size, void* d_ws, size_t ws_size,
                              hipStream_t stream) {
  const float* audios   = (const float*)d_in[0];
  const float* enc_w    = (const float*)d_in[1];
  const float* enc_b    = (const float*)d_in[2];
  const float* bgamma   = (const float*)d_in[3];
  const float* bbeta    = (const float*)d_in[4];
  const float* bottle_w = (const float*)d_in[5];
  const float* bottle_b = (const float*)d_in[6];
  const float* c1_w     = (const float*)d_in[7];
  const float* c1_b     = (const float*)d_in[8];
  const float* p1       = (const float*)d_in[9];
  const float* g1_g     = (const float*)d_in[10];
  const float* g1_b     = (const float*)d_in[11];
  const float* dwp      = (const float*)d_in[12];
  const float* p2       = (const float*)d_in[13];
  const float* g2_g     = (const float*)d_in[14];
  const float* g2_b     = (const float*)d_in[15];
  const float* c2_w     = (const float*)d_in[16];
  const float* c2_b     = (const float*)d_in[17];
  const float* sep_w    = (const float*)d_in[18];
  const float* sep_b    = (const float*)d_in[19];
  const float* anchors  = (const float*)d_in[20];
  const float* dec_w    = (const float*)d_in[21];
  const float* dec_b    = (const float*)d_in[22];

  float* ws = (float*)d_ws;
  float* bfr   = ws + o_bfr;
  float* decB  = ws + o_decB;
  float* decBias = ws + o_decBias;
  float* biasF = ws + o_biasF;
  float* cf    = ws + o_cf;
  float* mag   = ws + o_mag;
  float* cosp  = ws + o_cosp;
  float* sinp  = ws + o_sinp;
  float* xln   = ws + o_xln;
  float* xbuf  = ws + o_x;
  float* ybuf  = ws + o_y;
  float* zbuf  = ws + o_z;
  float* gsum  = ws + o_gsum;
  float* accp  = ws + o_acc;
  float* attp  = ws + o_att;
  float* embp  = ws + o_emb;
  float* Afull = ws + o_Af;
  float* framesp = ws + o_fr;

  // zero atomic accumulators (gsum 1024 + attr acc 2688, contiguous)
  hipMemsetAsync((void*)gsum, 0, (1024 + (size_t)B_*16*21) * sizeof(float), stream);

  k_prep<<<(256*516 + 514*256 + 256 + 516 + 255)/256, 256, 0, stream>>>(
      enc_w, enc_b, dec_w, dec_b, bfr, decB, decBias, biasF);

  // frames GEMM: mix-on-load, [enc | spec] out, M=3976, N=516, K=256
  gemm3<2,0,false><<<dim3(9, 63), 256, 0, stream>>>(
      audios, bfr, biasF, cf, B_*T_, FRSTR, 256, 0, FRSTR,
      nullptr, nullptr, nullptr, nullptr, nullptr, nullptr, 256);

  k_cln<<<dim3(T_, B_), 256, 0, stream>>>(cf, bgamma, bbeta, mag, cosp, sinp, xln);

  // bottleneck: M=3976, N=256, K=385 (lda=388, zero-padded)
  gemm3<0,0,false><<<dim3(4, 63), 256, 0, stream>>>(
      xln, bottle_w, bottle_b, xbuf, B_*T_, BTL, FC, XSTR, BTL,
      nullptr, nullptr, nullptr, nullptr, nullptr, nullptr, 0);

  // TCN
  for (int i = 0; i < NB; i++){
    int dil = 1 << (i & 7);
    gemm3<0,1,true><<<dim3(8, 8, B_), 256, 0, stream>>>(
        xbuf, c1_w + (size_t)i*BTL*H_, c1_b + i*H_, ybuf, T_, H_, BTL, BTL, H_,
        nullptr, nullptr, nullptr, p1 + i*H_, gsum + i*32, nullptr, 0);
    k_dwconv<<<dim3(T_, B_), 256, 0, stream>>>(
        ybuf, dwp + (size_t)i*3*H_, g1_g + i*H_, g1_b + i*H_,
        gsum + i*32, p2 + i*H_, zbuf, gsum + i*32 + 16, dil);
    gemm3<1,2,false><<<dim3(4, 63), 256, 0, stream>>>(
        zbuf, c2_w + (size_t)i*H_*BTL, c2_b + i*BTL, xbuf, B_*T_, BTL, H_, H_, BTL,
        g2_g + i*H_, g2_b + i*H_, gsum + i*32 + 16, nullptr, nullptr, xbuf, 0);
  }

  // separator: M=3976, N=7700, K=256 (128-row tiles, unchanged)
  gemm2<0,0,false><<<dim3(121, 32), 256, 0, stream>>>(
      xbuf, sep_w, sep_b, embp, B_*T_, FC*EMBED, BTL, BTL,
      nullptr, nullptr, nullptr, nullptr, nullptr, nullptr);

  // attractors
  k_attr2<<<dim3(ATTR_CH, B_*4), 256, 0, stream>>>(embp, anchors, accp);
  k_attrfin2<<<1, 128, 0, stream>>>(accp, attp);

  // decode: M=7952, N=256, K=514 (lda=516, zero-padded)
  k_afull<<<dim3(T_, B_), 256, 0, stream>>>(embp, cf, mag, cosp, sinp, attp, Afull);
  gemm3<0,0,false><<<dim3(4, 125), 256, 0, stream>>>(
      Afull, decB, decBias, framesp, 2*B_*T_, 256, 514, AFSTR, BTL,
      nullptr, nullptr, nullptr, nullptr, nullptr, nullptr, 0);
  k_ola<<<(B_*2*L_ + 255)/256, 256, 0, stream>>>(framesp, (float*)d_out);
}